// Round 1
// baseline (1980.544 us; speedup 1.0000x reference)
//
#include <hip/hip_runtime.h>

// Problem constants
#define NN 10          // nodes
#define NPAIRS 45      // 10 choose 2
#define BPW 16         // batches per workgroup
#define ROWS 160       // BPW * NN
#define DD 512         // feature dim
#define NCOLS 128      // 2*H (pa cols 0..63, pb cols 64..127)
#define BK 64          // K-chunk
#define KC_ITERS 8     // 512/64

typedef __attribute__((ext_vector_type(8))) __bf16 bf16x8;
typedef __attribute__((ext_vector_type(4))) float floatx4;

__constant__ unsigned char c_pairI[NPAIRS] = {
  0,0,0,0,0,0,0,0,0, 1,1,1,1,1,1,1,1, 2,2,2,2,2,2,2,
  3,3,3,3,3,3, 4,4,4,4,4, 5,5,5,5, 6,6,6, 7,7, 8};
__constant__ unsigned char c_pairJ[NPAIRS] = {
  1,2,3,4,5,6,7,8,9, 2,3,4,5,6,7,8,9, 3,4,5,6,7,8,9,
  4,5,6,7,8,9, 5,6,7,8,9, 6,7,8,9, 7,8,9, 8,9, 9};

// Pre-kernel: W1 (1024x64 fp32) -> fragment-major bf16 Wt in d_ws.
// Element order: [kc(8)][s(2)][nt(8)][lane(64)][j(8)]
//   value = W[n][k] where n = nt*16 + (lane&15), k = kc*64 + s*32 + (lane>>4)*8 + j
//   n < 64 -> W1a[k][n] = W1[k*64+n];  n >= 64 -> W1b[k][n-64] = W1[(512+k)*64+n-64]
__global__ void wprep_kernel(const float* __restrict__ W1, __bf16* __restrict__ wt) {
  int f = blockIdx.x * 256 + threadIdx.x;   // 0..65535
  int j    = f & 7;
  int lane = (f >> 3) & 63;
  int nt   = (f >> 9) & 7;
  int s    = (f >> 12) & 1;
  int kc   = (f >> 13);
  int n = nt * 16 + (lane & 15);
  int k = kc * 64 + s * 32 + (lane >> 4) * 8 + j;
  float v = (n < 64) ? W1[k * 64 + n] : W1[(512 + k) * 64 + (n - 64)];
  wt[f] = (__bf16)v;
}

__global__ __launch_bounds__(256, 2)
void fused_pair_mlp_kernel(const float* __restrict__ X, const __bf16* __restrict__ Wt,
                           const float* __restrict__ b1g, const float* __restrict__ W2g,
                           const float* __restrict__ b2g, float* __restrict__ out) {
  // LDS: region [0, 43520) = X staging (first 20480 B) later reused as P (160x136 bf16)
  //      region [43520, 49920) = out tile (1600 fp32)
  __shared__ __align__(16) unsigned char smem[43520 + 6400];
  bf16x8*         Xs  = (bf16x8*)smem;              // 1280 fragment slots of 16B
  unsigned short* Pl  = (unsigned short*)smem;      // 160 x 136 (padded) bf16
  float*          Ol  = (float*)(smem + 43520);     // 16 x 100 fp32

  const int tid  = threadIdx.x;
  const int lane = tid & 63;
  const int w    = tid >> 6;
  const size_t row0 = (size_t)blockIdx.x * ROWS;
  const float* Xb = X + row0 * DD;

  // diagonal zeros of the out tile (region disjoint from staging/P)
  if (tid < ROWS) {
    int b = tid / NN, n = tid - b * NN;
    Ol[b * 100 + n * 11] = 0.0f;
  }

  floatx4 zero4 = {0.0f, 0.0f, 0.0f, 0.0f};
  floatx4 acc0[10], acc1[10];
  #pragma unroll
  for (int mt = 0; mt < 10; ++mt) { acc0[mt] = zero4; acc1[mt] = zero4; }

  // Register prefetch of K-chunk 0: 5 units x 8 floats (32B contiguous per unit)
  float4 pf[10];
  #pragma unroll
  for (int it = 0; it < 5; ++it) {
    int u = it * 256 + tid;                       // 0..1279
    int m16 = u & 15, quad = (u >> 4) & 3, s = (u >> 6) & 1, mt = u >> 7;
    const float* src = Xb + (mt * 16 + m16) * DD + s * 32 + quad * 8;
    pf[2 * it]     = *(const float4*)src;
    pf[2 * it + 1] = *(const float4*)(src + 4);
  }

  for (int kc = 0; kc < KC_ITERS; ++kc) {
    // convert prefetched fp32 -> bf16, write fragment-major (lane-sequential b128)
    #pragma unroll
    for (int it = 0; it < 5; ++it) {
      int u = it * 256 + tid;
      float4 a = pf[2 * it], b = pf[2 * it + 1];
      bf16x8 v;
      v[0] = (__bf16)a.x; v[1] = (__bf16)a.y; v[2] = (__bf16)a.z; v[3] = (__bf16)a.w;
      v[4] = (__bf16)b.x; v[5] = (__bf16)b.y; v[6] = (__bf16)b.z; v[7] = (__bf16)b.w;
      Xs[u] = v;
    }
    __syncthreads();

    // issue next chunk's global loads now; in flight through the MFMA phase
    if (kc + 1 < KC_ITERS) {
      #pragma unroll
      for (int it = 0; it < 5; ++it) {
        int u = it * 256 + tid;
        int m16 = u & 15, quad = (u >> 4) & 3, s = (u >> 6) & 1, mt = u >> 7;
        const float* src = Xb + (mt * 16 + m16) * DD + (kc + 1) * 64 + s * 32 + quad * 8;
        pf[2 * it]     = *(const float4*)src;
        pf[2 * it + 1] = *(const float4*)(src + 4);
      }
    }

    // B fragments straight from L2-resident pre-converted Wt
    bf16x8 bf[2][2];
    #pragma unroll
    for (int s = 0; s < 2; ++s)
      #pragma unroll
      for (int t = 0; t < 2; ++t) {
        int fi = (kc * 2 + s) * 8 + (w * 2 + t);
        bf[s][t] = *(const bf16x8*)(Wt + (size_t)fi * 512 + lane * 8);
      }

    #pragma unroll
    for (int s = 0; s < 2; ++s) {
      #pragma unroll
      for (int mt = 0; mt < 10; ++mt) {
        bf16x8 a = Xs[mt * 128 + s * 64 + lane];
        acc0[mt] = __builtin_amdgcn_mfma_f32_16x16x32_bf16(a, bf[s][0], acc0[mt], 0, 0, 0);
        acc1[mt] = __builtin_amdgcn_mfma_f32_16x16x32_bf16(a, bf[s][1], acc1[mt], 0, 0, 0);
      }
    }
    __syncthreads();
  }

  // Spill P to LDS as bf16, layout [row][col], padded stride 136
  {
    int q = lane >> 4, c = lane & 15;
    #pragma unroll
    for (int mt = 0; mt < 10; ++mt) {
      #pragma unroll
      for (int reg = 0; reg < 4; ++reg) {
        int row = mt * 16 + q * 4 + reg;
        Pl[row * 136 + (w * 2 + 0) * 16 + c] =
            __builtin_bit_cast(unsigned short, (__bf16)acc0[mt][reg]);
        Pl[row * 136 + (w * 2 + 1) * 16 + c] =
            __builtin_bit_cast(unsigned short, (__bf16)acc1[mt][reg]);
      }
    }
  }
  __syncthreads();

  // Pair epilogue: half-wave per (b, pair); lane handles h = 2*h2, 2*h2+1
  {
    int h2 = lane & 31, half = lane >> 5;
    float b1a = b1g[2 * h2], b1b = b1g[2 * h2 + 1];
    float w2a = W2g[2 * h2], w2b = W2g[2 * h2 + 1];
    float b2v = b2g[0];
    int p = 0;
    for (int it2 = 0; it2 < 90; ++it2) {
      int bb = w * 4 + half + ((it2 < 45) ? 0 : 2);
      int i = c_pairI[p], j = c_pairJ[p];
      unsigned int ua = *(const unsigned int*)(Pl + (bb * 10 + i) * 136 + 2 * h2);
      unsigned int ub = *(const unsigned int*)(Pl + (bb * 10 + j) * 136 + 64 + 2 * h2);
      float pa0 = __builtin_bit_cast(float, ua << 16);
      float pa1 = __builtin_bit_cast(float, ua & 0xFFFF0000u);
      float pb0 = __builtin_bit_cast(float, ub << 16);
      float pb1 = __builtin_bit_cast(float, ub & 0xFFFF0000u);
      float v = fmaxf(pa0 + pb0 + b1a, 0.0f) * w2a +
                fmaxf(pa1 + pb1 + b1b, 0.0f) * w2b;
      #pragma unroll
      for (int m = 1; m < 32; m <<= 1) v += __shfl_xor(v, m, 64);
      if (h2 == 0) {
        float vv = v + b2v;
        Ol[bb * 100 + i * 10 + j] = vv;
        Ol[bb * 100 + j * 10 + i] = vv;
      }
      p = (p == 44) ? 0 : p + 1;
    }
  }
  __syncthreads();

  // Coalesced tile store: 16 batches x 100 floats = 400 float4
  {
    float4* og = (float4*)(out + (size_t)blockIdx.x * 1600);
    const float4* ol = (const float4*)Ol;
    for (int u = tid; u < 400; u += 256) og[u] = ol[u];
  }
}

extern "C" void kernel_launch(void* const* d_in, const int* in_sizes, int n_in,
                              void* d_out, int out_size, void* d_ws, size_t ws_size,
                              hipStream_t stream) {
  const float* X  = (const float*)d_in[0];
  const float* W1 = (const float*)d_in[1];
  const float* b1 = (const float*)d_in[2];
  const float* W2 = (const float*)d_in[3];
  const float* b2 = (const float*)d_in[4];
  float* out = (float*)d_out;
  __bf16* wt = (__bf16*)d_ws;   // 65536 bf16 = 128 KB

  int Btotal = in_sizes[0] / (NN * DD);   // 65536
  int blocks = Btotal / BPW;              // 4096

  wprep_kernel<<<dim3(256), dim3(256), 0, stream>>>(W1, wt);
  fused_pair_mlp_kernel<<<dim3(blocks), dim3(256), 0, stream>>>(
      X, (const __bf16*)wt, b1, W2, b2, out);
}